// Round 12
// baseline (586.425 us; speedup 1.0000x reference)
//
#include <hip/hip_runtime.h>
#include <math.h>

// ---------------- constants ----------------
#define DTMEM 0.1f   // DT*TAU_MEM_INV
#define DTSYN 0.2f   // DT*TAU_SYN_INV
#define DTTR  0.02f  // DT*TAU_PRE_INV == DT*TAU_POST_INV

static constexpr int B = 32, T = 32;
static constexpr int HD = 60, HP = 28;
static constexpr int LD = HD*HD, LP = HP*HP;

// lif0 state: slot-major [b][og:8][yh:2][i:7][tid:448] float4 (v0.x,v0.y,i0.x,i0.y)
static constexpr size_t SVI = (size_t)B*8*2*7*448*4;
// tq1: slot-major float2
static constexpr size_t SST = (size_t)B*8*2*7*448*2;
// conv2 state: slot-major [b][jgg:7][slot:6][tid:384] float4
static constexpr size_t S2  = (size_t)B*7*6*384*4;

// ---- workspace offsets (floats) ----
static constexpr size_t OW1A  = 0;                         // w1 ping (1500)
static constexpr size_t OW1B  = OW1A + 1500;               // w1 pong
static constexpr size_t OVI0  = OW1B + 1500;               // zero-region start
static constexpr size_t OTQ1  = OVI0 + SVI;
static constexpr size_t OTP2  = OTQ1 + SST;                // [B,30,28,28] master
static constexpr size_t OZ3A  = OTP2 + (size_t)B*30*LP;    // z3 ping
static constexpr size_t OZ3B  = OZ3A + (size_t)B*30*LP;    // z3 pong
static constexpr size_t OV1S  = OZ3B + (size_t)B*30*LP;
static constexpr size_t OI1S  = OV1S + S2;
static constexpr size_t OTQ2S = OI1S + S2;
static constexpr size_t OPHIA = OTQ2S + S2;                // u16 planes (376320 floats each)
static constexpr size_t OPLOA = OPHIA + 376320;
static constexpr size_t OPZ3A = OPLOA + 376320;
static constexpr size_t OPHIB = OPZ3A + 376320;
static constexpr size_t OPLOB = OPHIB + 376320;
static constexpr size_t OPZ3B = OPLOB + 376320;
static constexpr size_t OZEROEND = OPZ3B + 376320;         // zeroed by k_zero (gated!)
// precomputed DoG output + tp1 trace, all steps: [T][B][3600] each (fully written by k_pre)
static constexpr size_t OZALL  = OZEROEND;
static constexpr size_t OTPALL = OZALL + (size_t)T*B*3600;
static constexpr size_t OEPA  = OTPALL + (size_t)T*B*3600; // E partials [32][75000] f32
static constexpr size_t OEMA  = OEPA + (size_t)B*75000;
static constexpr size_t OEPB  = OEMA + (size_t)B*75000;
static constexpr size_t OEMB  = OEPB + (size_t)B*75000;
static constexpr size_t OPARTA = OEMB + (size_t)B*75000;   // part [64 slots][1500] (slot-major)
static constexpr size_t OPARTB = OPARTA + 96000;
static constexpr size_t OG    = OPARTB + 96000;            // [T][3200] (pre-zeroed!)
static constexpr size_t OHH   = OG + (size_t)T*3200;       // [T][500]
static constexpr size_t OW2A  = OHH + (size_t)T*500;       // w2 ping [100][30][28]
static constexpr size_t OW2B  = OW2A + 84000;
static constexpr size_t OCNZA = OW2B + 84000;              // int[960][4]
static constexpr size_t OCNZB = OCNZA + 3840;
static constexpr size_t OQZF  = OCNZB + 3840;              // int[512]
static constexpr size_t OPZF  = OQZF + 512;                // int[960]
static constexpr size_t OSZF  = OPZF + 960;                // int[224]
static constexpr size_t OEAA  = OSZF + 224;                // int[224] eact ping
static constexpr size_t OEAB  = OEAA + 224;                // int[224] eact pong
// corr A-plane half-1 global scratch: u16[224][8][576] each
static constexpr size_t OATH  = OEAB + 224;                // 516096 floats
static constexpr size_t OATL  = OATH + 516096;
static constexpr size_t OSPK  = OATL + 516096;             // int: any-LIF0-spike flag
static constexpr size_t OEND  = OSPK + 16;

struct DK { float v[25]; };

typedef __attribute__((ext_vector_type(8))) short bfx8;
typedef __attribute__((ext_vector_type(4))) float f32x4;

static __device__ __forceinline__ unsigned short f2bf(float f) {
    unsigned u = __float_as_uint(f);
    return (unsigned short)((u + 0x7FFFu + ((u >> 16) & 1u)) >> 16);
}
static __device__ __forceinline__ float bf2f(unsigned short h) {
    return __uint_as_float(((unsigned)h) << 16);
}

// STDP w1 pair update; part is slot-major [s:64][1500] -> coalesced row reads.
static __device__ __forceinline__ float2 w1pair(const float* w1cur, const float* pprev,
                                                int o, int pp, int t) {
    float wa = w1cur[o*50 + pp], wb = w1cur[o*50 + 25 + pp];
    if (t > 0) {
        float EpS = 0.f, EmS = 0.f;
        for (int s = 0; s < 64; ++s) {
            EpS += pprev[s*1500 + o*50 + pp];
            EmS += pprev[s*1500 + o*50 + 25 + pp];
        }
        wa = fminf(fmaxf(wa + 0.004f*fmaxf(1.f-wa,0.f)*EpS - 0.003f*fmaxf(wa,0.f)*EmS, 0.f), 1.f);
        wb = fminf(fmaxf(wb + 0.004f*fmaxf(1.f-wb,0.f)*(-EpS) - 0.003f*fmaxf(wb,0.f)*(-EmS), 0.f), 1.f);
    }
    return make_float2(wa, wb);
}

// STDP w2 update for one element; e = (j*30+c)*25+p.
static __device__ __forceinline__ float w2eff(float w, int e, int jgg,
        const int* eaR, const float* EPr, const float* EMr) {
    float ep = 0.f, em = 0.f; int any = 0;
    for (int bb = 0; bb < 32; ++bb) {
        if (eaR[bb*7 + jgg]) {
            any = 1;
            ep += EPr[(size_t)bb*75000 + e];
            em += EMr[(size_t)bb*75000 + e];
        }
    }
    if (!any) return w;
    float dwp = 0.004f * fmaxf(1.0f - w, 0.0f) * ep;
    float dwm = 0.003f * fmaxf(w, 0.0f) * em;
    return fminf(fmaxf(w + dwp - dwm, 0.0f), 1.0f);
}

union SMEM {
    struct {                              // front blocks (~29.3 KB)
        float zsh[32*60];
        float tsh[32*60];
        float red[700];
        float wd[100];
        float vish[448*4];                // vi0 staged (v.x,v.y,i.x,i.y per thread slot)
        float tqsh[448*2];                // tq1 staged / updated trace for pass-1
        int   sflags[8];
    } f;
    struct {                              // conv2+corr blocks (~41.1 KB)
        union { float spre[LP]; unsigned short sB[10656]; } u;  // conv stage | B-planes(10080)+zero(576)
        unsigned short aTH[8*576], aTL[8*576];                  // tq2 hi/lo A-planes, half (8 rows)
        unsigned int aZ4b[16*18];                               // z4 A-plane, bit-packed [16 rows][18 words]
        int sjany[16];
        int sany, sAnyTq, ganyJ;
        int sCA[30];
    } v;
};

// ================= k_pre: DoG + tp1 trace for ALL timesteps (input-only chain) =========
// Double-buffered x staging: 1 barrier/step. Same FMA order / trace recurrence as before.
__global__ __launch_bounds__(384) void k_pre(
        const float* __restrict__ x, const float* __restrict__ b1,
        const float* __restrict__ b2, float* __restrict__ zall,
        float* __restrict__ tpall, DK dk) {
    __shared__ __attribute__((aligned(16))) float xsh[2][10*64];
    int g = blockIdx.x, b = blockIdx.y, tid = threadIdx.x;
    int r0 = g*6;
    bool valid = tid < 360;
    int lr = tid / 60, col = tid - lr*60;
    float tp = 0.f;
    float bias = b1[0] - b2[0];
    if (tid < 160) {
        const float4* xs = (const float4*)(x + ((size_t)b)*4096 + (size_t)r0*64);
        ((float4*)xsh[0])[tid] = xs[tid];
    }
    __syncthreads();
    #pragma unroll 1
    for (int t = 0; t < T; ++t) {
        const float* xc = xsh[t & 1];
        if (t + 1 < T && tid < 160) {
            const float4* xs = (const float4*)(x + ((size_t)(t+1)*B + b)*4096 + (size_t)r0*64);
            ((float4*)xsh[(t+1) & 1])[tid] = xs[tid];
        }
        if (valid) {
            float a = 0.f;
            #pragma unroll
            for (int kh = 0; kh < 5; kh++)
                #pragma unroll
                for (int kw = 0; kw < 5; kw++)
                    a = fmaf(dk.v[kh*5+kw], xc[(lr+kh)*64 + col + kw], a);
            float zv = a + bias;
            tp = tp + DTTR*(zv - tp);
            size_t o = ((size_t)t*B + b)*3600 + (size_t)g*360 + tid;
            zall[o] = zv;
            tpall[o] = tp;
        }
        __syncthreads();
    }
}

// ================= k_sim: speculative LIF0 replay — sets flag if ANY spike would fire ====
// v2: 896 threads (7 px/thread, 2x occupancy), double-buffered z staging (1 barrier/step).
// Bit-identical spike trajectory: same per-pixel kh-outer/kw-inner FMA chain, t=0 raw w1,
// t>=1 clamp(w1) (exact while no spike has occurred — part sums provably zero).
__global__ __launch_bounds__(896) void k_sim(
        const float* __restrict__ zall, const float* __restrict__ w1,
        int* __restrict__ spk) {
    __shared__ __attribute__((aligned(16))) float zsh[2][1920];
    __shared__ float wd0[100], wdC[100];
    const int og = blockIdx.x & 7, by = blockIdx.x >> 3;
    const int b = by >> 1, yh = by & 1, y0 = yh*28;
    const int tid = threadIdx.x;
    if (tid < 100) {
        int oo2 = tid / 25, pp = tid % 25;
        int o2 = og*4 + oo2; if (o2 > 29) o2 = 29;
        float wa = w1[o2*50 + pp], wb = w1[o2*50 + 25 + pp];
        wd0[tid] = wa - wb;
        wdC[tid] = fminf(fmaxf(wa, 0.f), 1.f) - fminf(fmaxf(wb, 0.f), 1.f);
    }
    int oo = tid & 3, xq = (tid >> 2) & 7, yv = tid >> 5;   // 4 x 8 x 28
    int o = og*4 + oo;
    bool valid = (o < 30);
    int c0 = xq*7;               // 7 output px: c0..c0+6; window cols c0..c0+10
    int cb2 = c0 & ~1;           // even float base -> aligned float2 reads
    int off = c0 & 1;
    float v[7], ci[7];
    #pragma unroll
    for (int k = 0; k < 7; ++k) { v[k] = 0.f; ci[k] = 0.f; }
    bool any = false;
    if (tid < 480) {
        const float4* zs = (const float4*)(zall + ((size_t)b)*3600 + (size_t)y0*60);
        ((float4*)zsh[0])[tid] = zs[tid];
    }
    __syncthreads();
    #pragma unroll 1
    for (int t = 0; t < T; ++t) {
        const float* zc = zsh[t & 1];
        if (t + 1 < T && tid < 480) {
            const float4* zs = (const float4*)(zall + ((size_t)(t+1)*B + b)*3600 + (size_t)y0*60);
            ((float4*)zsh[(t+1) & 1])[tid] = zs[tid];
        }
        if (valid) {
            float acc[7];
            #pragma unroll
            for (int k = 0; k < 7; k++) acc[k] = 0.f;
            const float* wdp = (t == 0) ? wd0 : wdC;
            #pragma unroll
            for (int kh = 0; kh < 5; kh++) {
                float rr[12];
                const float2* r2 = (const float2*)&zc[(yv+kh)*HD + cb2];
                #pragma unroll
                for (int i = 0; i < 6; i++) ((float2*)rr)[i] = r2[i];
                #pragma unroll
                for (int kw = 0; kw < 5; kw++) {
                    float w = wdp[oo*25 + kh*5 + kw];
                    #pragma unroll
                    for (int k = 0; k < 7; k++) acc[k] = fmaf(w, rr[off + k + kw], acc[k]);
                }
            }
            #pragma unroll
            for (int e = 0; e < 7; ++e) {
                float vd = v[e] + DTMEM*(ci[e] - v[e]);
                float z = (vd > 15.0f) ? 1.0f : 0.0f;
                any = any || (z != 0.f);
                v[e] = (1.0f - z)*vd;
                ci[e] = (ci[e] - DTSYN*ci[e]) + acc[e];
            }
        }
        __syncthreads();
    }
    if (any) atomicOr(spk, 1);
}

// ================= k_zero: zero the state region, ONLY when slow path is needed =========
__global__ __launch_bounds__(256) void k_zero(float* __restrict__ ws) {
    if (((const int*)(ws + OSPK))[0] == 0) return;
    const size_t n = (OZEROEND - OVI0) / 4;   // float4 count (region is 16B-divisible)
    float4* p = (float4*)(ws + OVI0);
    float4 z; z.x = 0.f; z.y = 0.f; z.z = 0.f; z.w = 0.f;
    for (size_t i = (size_t)blockIdx.x*blockDim.x + threadIdx.x; i < n;
         i += (size_t)gridDim.x*blockDim.x)
        p[i] = z;
}

// ================= one launch per timestep, grid 736 =================
// All blocks first check the speculation flag: if no LIF0 spike ever fires, the entire
// step loop is dead (g pre-zeroed; nothing else consumed) and blocks exit immediately.
__global__ __launch_bounds__(448) void k_step(float* __restrict__ ws, int t) {
    __shared__ __attribute__((aligned(16))) SMEM sm;
    const int blk = blockIdx.x, tid = threadIdx.x;
    if (((const int*)(ws + OSPK))[0] == 0) return;   // speculation: zero-activity fast path

    if (blk < 224) {
        // ===================== conv2 + corr, step u = t-1 =====================
        const int u = t - 1;
        if (u < 0) return;
        const int cb = blk;
        const int jgg = cb % 7, b = cb / 7, jb0 = jgg*16;
        const float* w2cur = ws + ((u&1) ? OW2B : OW2A);
        float*       w2nxt = ws + ((u&1) ? OW2A : OW2B);
        const float* EPr = ws + ((u&1) ? OEPA : OEPB);   // E(u-1)
        const float* EMr = ws + ((u&1) ? OEMA : OEMB);
        float*       EPw = ws + ((u&1) ? OEPB : OEPA);   // E(u)
        float*       EMw = ws + ((u&1) ? OEMB : OEMA);
        const int*   eaR = (const int*)(ws + ((u&1) ? OEAA : OEAB));
        int*         eaW = (int*)(ws + ((u&1) ? OEAB : OEAA));
        const int*   cnzP = (const int*)(ws + ((u&1) ? OCNZB : OCNZA));
        const float* z3r = ws + ((u&1) ? OZ3B : OZ3A);
        const unsigned short* uhiR = (const unsigned short*)(ws + ((u&1) ? OPHIB : OPHIA));
        const unsigned short* uloR = (const unsigned short*)(ws + ((u&1) ? OPLOB : OPLOA));
        const unsigned short* uz3R = (const unsigned short*)(ws + ((u&1) ? OPZ3B : OPZ3A));
        unsigned short* gTH = (unsigned short*)(ws + OATH) + (size_t)cb*8*576;
        unsigned short* gTL = (unsigned short*)(ws + OATL) + (size_t)cb*8*576;
        int* szf = (int*)(ws + OSZF);
        float* g_t = ws + OG + (size_t)u*3200;

        // w2 persist (through u-1) — must run even on early-out
        if (u < 31) {
            int e = cb*448 + tid;
            if (e < 75000) {
                int j = e/750, r = e - j*750, c = r/25, p25 = r - c*25;
                size_t f = ((size_t)j*30 + c)*28 + p25;
                float w = w2cur[f];
                if (u >= 1) w = w2eff(w, e, j>>4, eaR, EPr, EMr);
                w2nxt[f] = w;
            }
        }

        if (tid == 0) { sm.v.sany = 0; sm.v.sAnyTq = 0; sm.v.ganyJ = 0; }
        if (tid < 16) sm.v.sjany[tid] = 0;
        for (int i2 = tid; i2 < 288; i2 += 448) sm.v.aZ4b[i2] = 0u;
        __syncthreads();
        if (tid < 120 && cnzP[b*120 + tid]) atomicOr(&sm.v.sany, 1);
        if (tid < 30) {
            const int* cz = cnzP + (b*30 + tid)*4;
            sm.v.sCA[tid] = (cz[0] | cz[1] | cz[2] | cz[3]);
        }
        if (u >= 1 && tid < 32 && eaR[tid*7 + jgg]) atomicOr(&sm.v.ganyJ, 1);
        __syncthreads();
        const int szv = szf[b*7 + jgg];
        if (szv && !sm.v.sany) {
            if (tid < 16 && jb0 + tid < 100) g_t[b*100 + jb0 + tid] = 0.f;
            if (u < 31 && tid == 0) eaW[b*7 + jgg] = 0;
            return;
        }
        // ---- conv2 (384 threads: jp:8, xh:2, y:24); j-pair processed sequentially ----
        const bool run = tid < 384;
        int jp = tid & 7, xh = (tid >> 3) & 1, yv = tid >> 4;
        int j0 = jb0 + jp*2;
        int ja = (j0 < 100) ? j0 : 99, jbb = (j0+1 < 100) ? j0+1 : 99;
        int xx0 = xh*12;
        float acc0[12], acc1[12];
        #pragma unroll
        for (int xq = 0; xq < 12; xq++) { acc0[xq] = 0.f; acc1[xq] = 0.f; }
        const int gJ = sm.v.ganyJ;
        #pragma unroll 1
        for (int c = 0; c < 30; ++c) {
            bool act = sm.v.sCA[c] != 0;
            __syncthreads();
            if (act) {
                const float4* src = (const float4*)(z3r + (size_t)(b*30 + c)*LP);
                for (int i2 = tid; i2 < 196; i2 += 448) ((float4*)sm.v.u.spre)[i2] = src[i2];
            }
            __syncthreads();
            if (!act) continue;
            if (run) {
                #pragma unroll 1
                for (int jj = 0; jj < 2; ++jj) {
                    int jc = jj ? jbb : ja;
                    float wa[28];
                    #pragma unroll
                    for (int i = 0; i < 7; i++)
                        ((float4*)wa)[i] = ((const float4*)(w2cur + ((size_t)jc*30 + c)*28))[i];
                    if (u >= 1 && gJ) {
                        #pragma unroll
                        for (int p25 = 0; p25 < 25; p25++)
                            wa[p25] = w2eff(wa[p25], (jc*30 + c)*25 + p25, jc>>4, eaR, EPr, EMr);
                    }
                    float* accp = jj ? acc1 : acc0;
                    #pragma unroll
                    for (int kh = 0; kh < 5; kh++) {
                        float rr[16];
                        const float4* r4 = (const float4*)&sm.v.u.spre[(yv+kh)*HP + xx0];
                        #pragma unroll
                        for (int i = 0; i < 4; i++) ((float4*)rr)[i] = r4[i];
                        #pragma unroll
                        for (int kw = 0; kw < 5; kw++) {
                            float w0 = wa[kh*5+kw];
                            #pragma unroll
                            for (int xq = 0; xq < 12; xq++)
                                accp[xq] = fmaf(w0, rr[xq+kw], accp[xq]);
                        }
                    }
                }
            }
        }
        // ---- LIF1 + tq2 + A-plane emit (half LDS / half global scratch) ----
        bool spk0 = false, spk1 = false, anyTq = false;
        if (run) {
            float4* v1p = (float4*)(ws + OV1S);
            float4* i1p = (float4*)(ws + OI1S);
            float4* t2p = (float4*)(ws + OTQ2S);
            size_t sb2 = ((size_t)(b*7 + jgg)*6)*384 + tid;
            #pragma unroll
            for (int jj = 0; jj < 2; jj++) {
                bool anyspk = false;
                int rj = jp*2 + jj;
                #pragma unroll
                for (int i = 0; i < 3; i++) {
                    size_t si = sb2 + (size_t)(jj*3 + i)*384;
                    float4 v4 = v1p[si];
                    float4 c4 = i1p[si];
                    float4 t4 = t2p[si];
                    float4 vn, in, tn4;
                    float* vp=(float*)&v4; float* cp=(float*)&c4; float* tp=(float*)&t4;
                    float* vnp=(float*)&vn; float* inp=(float*)&in; float* tnp=(float*)&tn4;
                    unsigned zb4 = 0;
                    #pragma unroll
                    for (int k = 0; k < 4; k++) {
                        float a = jj ? acc1[i*4+k] : acc0[i*4+k];
                        float vd = vp[k] + DTMEM*(cp[k] - vp[k]);
                        float z = (vd > 10.0f) ? 1.0f : 0.0f;
                        vnp[k] = (1.0f - z)*vd;
                        inp[k] = (cp[k] - DTSYN*cp[k]) + 10.0f*a;
                        tnp[k] = tp[k] + DTTR*(z - tp[k]);
                        if (z != 0.f) { zb4 |= 1u << k; anyspk = true; }
                        anyTq = anyTq || (tnp[k] != 0.f);
                    }
                    v1p[si] = vn;
                    i1p[si] = in;
                    t2p[si] = tn4;
                    int col = yv*24 + xx0 + i*4;
                    if (zb4) atomicOr(&sm.v.aZ4b[rj*18 + (col >> 5)], zb4 << (col & 31));
                    ushort4 hb, lb4;
                    unsigned short h;
                    h = f2bf(tnp[0]); hb.x = h; lb4.x = f2bf(tnp[0] - bf2f(h));
                    h = f2bf(tnp[1]); hb.y = h; lb4.y = f2bf(tnp[1] - bf2f(h));
                    h = f2bf(tnp[2]); hb.z = h; lb4.z = f2bf(tnp[2] - bf2f(h));
                    h = f2bf(tnp[3]); hb.w = h; lb4.w = f2bf(tnp[3] - bf2f(h));
                    if (rj < 8) {
                        *(ushort4*)&sm.v.aTH[rj*576 + col] = hb;
                        *(ushort4*)&sm.v.aTL[rj*576 + col] = lb4;
                    } else {
                        size_t gb = (size_t)(rj - 8)*576 + col;
                        *(ushort4*)(gTH + gb) = hb;
                        *(ushort4*)(gTL + gb) = lb4;
                    }
                }
                if (jj == 0) spk0 = anyspk; else spk1 = anyspk;
            }
            if (spk0 && j0 < 100) atomicOr(&sm.v.sjany[jp*2], 1);
            if (spk1 && j0+1 < 100) atomicOr(&sm.v.sjany[jp*2+1], 1);
            if (anyTq) atomicOr(&sm.v.sAnyTq, 1);
        }
        __syncthreads();
        if (tid < 16 && jb0 + tid < 100) g_t[b*100 + jb0 + tid] = sm.v.sjany[tid] ? 1.f : 0.f;
        if (tid == 0 && szv) szf[b*7 + jgg] = 0;
        // ---- STDP correlations, two 8-row passes (E(u) not needed at u==31) ----
        if (u < 31) {
            int m0i = 0;
            #pragma unroll
            for (int k = 0; k < 16; k++) m0i |= sm.v.sjany[k];
            bool m0 = (m0i != 0);
            bool mq = (sm.v.sAnyTq != 0);
            bool ea = m0 || mq;
            if (tid == 0) eaW[b*7 + jgg] = ea ? 1 : 0;
            if (!ea) return;
            for (int i2 = tid; i2 < 576; i2 += 448) sm.v.u.sB[10080 + i2] = 0;  // zero block
            int lane = tid & 63, wv = tid >> 6;
            int mode = wv >> 1, n = wv & 1;
            bool wact = (wv < 4);
            int r = lane & 15;
            bool r8 = (r < 8);
            int g8 = (lane >> 4) * 8;
            int p25 = n*16 + r;
            int offB1, offB2;
            {
                int offH, offL, offZ;
                if (p25 < 25) {
                    int dy = p25/5, dx = p25 - dy*5;
                    offH = ((0*5 + dx)*672 + dy*24)*2;
                    offL = ((1*5 + dx)*672 + dy*24)*2;
                    offZ = ((2*5 + dx)*672 + dy*24)*2;
                } else { offH = offL = offZ = 10080*2; }
                offB1 = (mode == 0) ? offH : offZ;
                offB2 = (mode == 0) ? offL : offZ;
            }
            float* Ew = (mode == 0) ? EPw : EMw;
            const char* sBb = (const char*)sm.v.u.sB;
            #pragma unroll 1
            for (int h = 0; h < 2; ++h) {
                if (h == 1) {
                    __syncthreads();   // pass-0 MFMA done before overwriting aTH/aTL
                    for (int i2 = tid; i2 < 1152; i2 += 448) {
                        if (i2 < 576) ((uint4*)sm.v.aTH)[i2] = ((const uint4*)gTH)[i2];
                        else ((uint4*)sm.v.aTL)[i2-576] = ((const uint4*)gTL)[i2-576];
                    }
                }
                int m0h = sm.v.sjany[h*8+0] | sm.v.sjany[h*8+1] | sm.v.sjany[h*8+2] |
                          sm.v.sjany[h*8+3] | sm.v.sjany[h*8+4] | sm.v.sjany[h*8+5] |
                          sm.v.sjany[h*8+6] | sm.v.sjany[h*8+7];
                #pragma unroll 1
                for (int c = 0; c < 30; ++c) {
                    bool cAc = sm.v.sCA[c] != 0;
                    __syncthreads();
                    {   // stage B-planes for this c
                        const size_t pbase = (size_t)(b*30 + c)*784;
                        for (int idx = tid; idx < 784; idx += 448) {
                            int rw = idx/28, col = idx - rw*28;
                            #pragma unroll
                            for (int pl = 0; pl < 3; ++pl) {
                                bool need = (pl < 2) ? m0 : (cAc && mq);
                                if (!need) continue;
                                unsigned short vvv =
                                    ((pl == 0) ? uhiR : (pl == 1) ? uloR : uz3R)[pbase + idx];
                                int base = pl*5*672 + rw*24;
                                #pragma unroll
                                for (int dx = 0; dx < 5; ++dx) {
                                    int xx = col - dx;
                                    if (xx >= 0 && xx < 24) sm.v.u.sB[base + dx*672 + xx] = vvv;
                                }
                            }
                        }
                    }
                    __syncthreads();
                    if (!wact) continue;
                    f32x4 C = (f32x4){0.f, 0.f, 0.f, 0.f};
                    bool go = (mode == 0) ? (m0h != 0) : (mq && cAc);
                    if (go) {
                        for (int ks = 0; ks < 18; ++ks) {
                            int kk = ks*32 + g8;
                            bfx8 a1 = {}, a2 = {};
                            if (mode == 0) {
                                unsigned wbits = 0;
                                if (r8) wbits = sm.v.aZ4b[(h*8 + r)*18 + ks] >> g8;
                                #pragma unroll
                                for (int k = 0; k < 8; ++k)
                                    ((short*)&a1)[k] = ((wbits >> k) & 1u) ? (short)0x3F80 : (short)0;
                                a2 = a1;
                            } else if (r8) {
                                a1 = *(const bfx8*)(sm.v.aTH + r*576 + ks*32);
                                a2 = *(const bfx8*)(sm.v.aTL + r*576 + ks*32);
                            }
                            bfx8 b1v = *(const bfx8*)(sBb + offB1 + kk*2);
                            bfx8 b2v = *(const bfx8*)(sBb + offB2 + kk*2);
                            C = __builtin_amdgcn_mfma_f32_16x16x32_bf16(a1, b1v, C, 0, 0, 0);
                            C = __builtin_amdgcn_mfma_f32_16x16x32_bf16(a2, b2v, C, 0, 0, 0);
                        }
                    }
                    if (p25 < 25 && (lane >> 4) < 2) {
                        #pragma unroll
                        for (int q = 0; q < 4; ++q) {
                            int j = jb0 + h*8 + (lane >> 4)*4 + q;
                            if (j < 100)
                                Ew[(size_t)b*75000 + ((size_t)j*30 + c)*25 + p25] = C[q];
                        }
                    }
                }
            }
        }
        return;
    }

    // ===================== front, step t =====================
    if (t >= T) return;
    const int fb = blk - 224;
    const int og = fb & 7, by = fb >> 3;
    const int b = by >> 1, yh = by & 1, y0 = yh*28;

    const float* w1cur = ws + ((t&1) ? OW1B : OW1A);
    float*       w1nxt = ws + ((t&1) ? OW1A : OW1B);
    float*       partW = ws + ((t&1) ? OPARTB : OPARTA);
    const float* pprev = ws + ((t&1) ? OPARTA : OPARTB);
    int*         cnzW  = (int*)(ws + ((t&1) ? OCNZB : OCNZA));
    float*       z3W   = ws + ((t&1) ? OZ3B : OZ3A);
    unsigned short* uhiW = (unsigned short*)(ws + ((t&1) ? OPHIB : OPHIA));
    unsigned short* uloW = (unsigned short*)(ws + ((t&1) ? OPLOB : OPLOA));
    unsigned short* uz3W = (unsigned short*)(ws + ((t&1) ? OPZ3B : OPZ3A));
    float* vi0g = ws + OVI0; float* tq1g = ws + OTQ1;
    float* tp2g = ws + OTP2;
    int* qzf = (int*)(ws + OQZF);
    int* pzf = (int*)(ws + OPZF);

    const int prow = (b*2 + yh)*1500;   // this block's part row (slot-major)
    int qzOld = qzf[(b*8 + og)*2 + yh];
    size_t sb = ((size_t)((b*8 + og)*2 + yh)*7)*448 + tid;
    float4* vi0p = (float4*)vi0g;
    float2* tq1p = (float2*)tq1g;
    {
        // batch all global staging: precomputed z/tp1 rows + vi0 (+tq1 if nonzero)
        const float4* zs = (const float4*)(ws + OZALL + ((size_t)t*B + b)*3600 + (size_t)y0*60);
        const float4* ts = (const float4*)(ws + OTPALL + ((size_t)t*B + b)*3600 + (size_t)y0*60);
        for (int i2 = tid; i2 < 480; i2 += 448) {
            ((float4*)sm.f.zsh)[i2] = zs[i2];
            ((float4*)sm.f.tsh)[i2] = ts[i2];
        }
        #pragma unroll
        for (int i = 0; i < 7; i++)
            ((float4*)sm.f.vish)[i*448 + tid] = vi0p[sb + (size_t)i*448];
        if (!qzOld) {
            #pragma unroll
            for (int i = 0; i < 7; i++)
                ((float2*)sm.f.tqsh)[i*448 + tid] = tq1p[sb + (size_t)i*448];
        }
    }
    if (tid < 100) {
        int oo2 = tid / 25, pp = tid % 25;
        int o2 = og*4 + oo2; if (o2 > 29) o2 = 29;
        float2 wp = w1pair(w1cur, pprev, o2, pp, t);
        sm.f.wd[tid] = wp.x - wp.y;
    }
    if (fb < 4) {
        int e = fb*448 + tid;
        if (e < 1500) {
            int o = e/50, r = e%50, ch = r/25, pp = r%25;
            float2 wp = w1pair(w1cur, pprev, o, pp, t);
            w1nxt[e] = ch ? wp.y : wp.x;
        }
    }
    if (tid < 8) sm.f.sflags[tid] = 0;
    __syncthreads();
    int oo = tid & 3, xq = (tid >> 2) & 3, yv = tid >> 4;
    int o = og*4 + oo, xx0 = xq*14;
    bool valid = (o < 30);
    unsigned zmask = 0;
    float qs = 0.f;
    bool anym = false;
    if (valid) {
        float acc[14];
        #pragma unroll
        for (int k = 0; k < 14; k++) acc[k] = 0.f;
        #pragma unroll
        for (int kh = 0; kh < 5; kh++) {
            float rr[18];
            const float2* r2 = (const float2*)&sm.f.zsh[(yv+kh)*HD + xx0];
            #pragma unroll
            for (int i = 0; i < 9; i++) ((float2*)rr)[i] = r2[i];
            #pragma unroll
            for (int kw = 0; kw < 5; kw++) {
                float w = sm.f.wd[oo*25 + kh*5 + kw];
                #pragma unroll
                for (int k = 0; k < 14; k++) acc[k] = fmaf(w, rr[k+kw], acc[k]);
            }
        }
        // LIF0: state from LDS (staged at top); updated v/i -> global;
        // updated trace -> tqsh (for pass-1) + gated global write.
        #pragma unroll
        for (int i = 0; i < 7; i++) {
            float4 vi = ((float4*)sm.f.vish)[i*448 + tid];
            float2 t2;
            if (qzOld) { t2.x = 0.f; t2.y = 0.f; }
            else t2 = ((float2*)sm.f.tqsh)[i*448 + tid];
            float4 vin;
            float2 tn2;
            bool sp = false;
            #pragma unroll
            for (int k = 0; k < 2; k++) {
                int e = i*2 + k;
                float vv = k ? vi.y : vi.x, cc = k ? vi.w : vi.z, tt = k ? t2.y : t2.x;
                float vd = vv + DTMEM*(cc - vv);
                float z = (vd > 15.0f) ? 1.0f : 0.0f;
                float vo = (1.0f - z)*vd;
                float io_ = (cc - DTSYN*cc) + acc[e];
                float tq = tt + DTTR*(z - tt);
                if (k) { vin.y = vo; vin.w = io_; tn2.y = tq; }
                else   { vin.x = vo; vin.z = io_; tn2.x = tq; }
                if (z != 0.f) { zmask |= 1u << e; sp = true; }
                qs += tq;
            }
            vi0p[sb + (size_t)i*448] = vin;
            ((float2*)sm.f.tqsh)[i*448 + tid] = tn2;   // own slot; no barrier needed
            if (!qzOld || sp) tq1p[sb + (size_t)i*448] = tn2;
        }
        float mx[7];
        #pragma unroll
        for (int k = 0; k < 7; k++) mx[k] = ((zmask >> (2*k)) & 3u) ? 1.0f : 0.0f;
        #pragma unroll
        for (int k = 0; k < 7; k++) {
            float pm = __shfl_xor(mx[k], 16, 64);   // y-partner (y^1)
            mx[k] = fmaxf(mx[k], pm);
        }
        if ((yv & 1) == 0) {
            int pzOld = pzf[b*30 + o];
            int py = yh*14 + (yv >> 1);
            size_t pb = ((size_t)(b*30 + o)*HP + py)*HP + xq*7;
            #pragma unroll
            for (int k = 0; k < 7; k++) {
                float m = mx[k];
                anym = anym || (m != 0.f);
                if (!pzOld || m != 0.f) {
                    z3W[pb + k] = m;
                    float tpv = pzOld ? 0.f : tp2g[pb + k];
                    float tnew = tpv + DTTR*(m - tpv);
                    tp2g[pb + k] = tnew;
                    unsigned short h = f2bf(tnew);
                    uhiW[pb + k] = h;
                    uloW[pb + k] = f2bf(tnew - bf2f(h));
                    uz3W[pb + k] = (m != 0.f) ? (unsigned short)0x3F80 : (unsigned short)0;
                }
            }
        }
    }
    if (anym) atomicOr(&sm.f.sflags[oo*2 + (xq >> 1)], 1);
    __syncthreads();
    int anyblk = sm.f.sflags[0]|sm.f.sflags[1]|sm.f.sflags[2]|sm.f.sflags[3]|
                 sm.f.sflags[4]|sm.f.sflags[5]|sm.f.sflags[6]|sm.f.sflags[7];
    if (tid < 8) {
        int o2 = og*4 + (tid >> 1);
        if (o2 < 30) cnzW[(b*30 + o2)*4 + yh*2 + (tid & 1)] = sm.f.sflags[tid];
    }
    if (tid < 4) {  // sticky plane-zero clear (benign cross-yh race: both write 0)
        int o2 = og*4 + tid;
        if (o2 < 30 && (sm.f.sflags[tid*2] | sm.f.sflags[tid*2+1])) pzf[b*30 + o2] = 0;
    }
    if (tid == 0 && qzOld && anyblk) qzf[(b*8 + og)*2 + yh] = 0;

    if (qzOld && !anyblk) {
        // tq1 was zero and no spikes fired: both correlation rows are exactly zero.
        if (tid < 100) {
            int oo2 = tid / 25, q = tid % 25;
            int o2 = og*4 + oo2;
            if (o2 < 30) {
                partW[prow + o2*50 + q] = 0.f;
                partW[prow + o2*50 + 25 + q] = 0.f;
            }
        }
        return;
    }
    int lane = tid & 63, wave = tid >> 6;
    // pass 1: minus correlation (unfold(z0) x tq1_new); tn re-read from LDS tqsh.
    {
        float a[25];
        #pragma unroll
        for (int pq = 0; pq < 25; pq++) a[pq] = 0.f;
        if (valid && qs != 0.f) {
            float tn[14];
            #pragma unroll
            for (int i = 0; i < 7; i++) {
                float2 t2 = ((float2*)sm.f.tqsh)[i*448 + tid];
                tn[2*i] = t2.x; tn[2*i+1] = t2.y;
            }
            #pragma unroll
            for (int kh = 0; kh < 5; kh++) {
                float rr[18];
                const float2* r2 = (const float2*)&sm.f.zsh[(yv+kh)*HD + xx0];
                #pragma unroll
                for (int i = 0; i < 9; i++) ((float2*)rr)[i] = r2[i];
                #pragma unroll
                for (int kw = 0; kw < 5; kw++)
                    #pragma unroll
                    for (int k = 0; k < 14; k++)
                        a[kh*5+kw] = fmaf(rr[k+kw], tn[k], a[kh*5+kw]);
            }
        }
        #pragma unroll
        for (int q = 0; q < 25; q++) {
            float v = a[q];
            v += __shfl_xor(v, 4, 64);
            v += __shfl_xor(v, 8, 64);
            v += __shfl_xor(v, 16, 64);
            v += __shfl_xor(v, 32, 64);
            if (lane < 4) sm.f.red[wave*100 + lane*25 + q] = v;
        }
    }
    __syncthreads();
    if (tid < 100) {
        int oo2 = tid / 25, q = tid % 25;
        float s = 0.f;
        #pragma unroll
        for (int w = 0; w < 7; w++) s += sm.f.red[w*100 + oo2*25 + q];
        int o2 = og*4 + oo2;
        if (o2 < 30) partW[prow + o2*50 + 25 + q] = s;
    }
    __syncthreads();
    // pass 2: plus correlation (unfold(tp1_new) x z2); z from zmask bits.
    {
        float a[25];
        #pragma unroll
        for (int pq = 0; pq < 25; pq++) a[pq] = 0.f;
        if (valid && zmask != 0u) {
            float zf[14];
            #pragma unroll
            for (int k = 0; k < 14; k++) zf[k] = ((zmask >> k) & 1u) ? 1.0f : 0.0f;
            #pragma unroll
            for (int kh = 0; kh < 5; kh++) {
                float rr[18];
                const float2* r2 = (const float2*)&sm.f.tsh[(yv+kh)*HD + xx0];
                #pragma unroll
                for (int i = 0; i < 9; i++) ((float2*)rr)[i] = r2[i];
                #pragma unroll
                for (int kw = 0; kw < 5; kw++)
                    #pragma unroll
                    for (int k = 0; k < 14; k++)
                        a[kh*5+kw] = fmaf(rr[k+kw], zf[k], a[kh*5+kw]);
            }
        }
        #pragma unroll
        for (int q = 0; q < 25; q++) {
            float v = a[q];
            v += __shfl_xor(v, 4, 64);
            v += __shfl_xor(v, 8, 64);
            v += __shfl_xor(v, 16, 64);
            v += __shfl_xor(v, 32, 64);
            if (lane < 4) sm.f.red[wave*100 + lane*25 + q] = v;
        }
    }
    __syncthreads();
    if (tid < 100) {
        int oo2 = tid / 25, q = tid % 25;
        float s = 0.f;
        #pragma unroll
        for (int w = 0; w < 7; w++) s += sm.f.red[w*100 + oo2*25 + q];
        int o2 = og*4 + oo2;
        if (o2 < 30) partW[prow + o2*50 + q] = s;
    }
}

// ================= k_prep: padded w2 + flag init (slow path only) =================
__global__ void k_prep(const float* __restrict__ w2, float* __restrict__ w2p,
                       int* __restrict__ qzf, int* __restrict__ pzf,
                       int* __restrict__ szf, const int* __restrict__ spk) {
    if (spk[0] == 0) return;   // fast path: none of these are ever read
    int e = blockIdx.x*blockDim.x + threadIdx.x;
    if (e < 75000) {
        int j = e / 750, r = e % 750, c = r / 25, p = r % 25;
        w2p[((size_t)j*30 + c)*28 + p] = w2[e];
    }
    if (e < 512) qzf[e] = 1;
    if (e < 960) pzf[e] = 1;
    if (e < 224) szf[e] = 1;
}

// ================= k_fc1b: batched fc1, grid (500 n, 4 t-quarters) =================
__global__ __launch_bounds__(256) void k_fc1b(
        const float* __restrict__ g_all, const float* __restrict__ fcw,
        const float* __restrict__ fcb, float* __restrict__ h_all,
        const int* __restrict__ spk) {
    __shared__ float red[8][4];
    int n = blockIdx.x, by = blockIdx.y, tid = threadIdx.x;
    if (spk[0] == 0) {
        // g is all-zero: h = 0*w (any order) + fcb = fcb, bit-exactly.
        if (tid < 8) h_all[(size_t)(by*8 + tid)*500 + n] = fcb[n];
        return;
    }
    const float4* w4 = (const float4*)(fcw + (size_t)n*3200);
    float4 wreg[4];
    #pragma unroll
    for (int i = 0; i < 4; i++) {
        int k = tid + 256*i;
        if (k < 800) wreg[i] = w4[k];
    }
    float accs[8];
    #pragma unroll
    for (int tt = 0; tt < 8; tt++) accs[tt] = 0.f;
    #pragma unroll 1
    for (int tt = 0; tt < 8; tt++) {
        int t = by*8 + tt;
        const float4* g4 = (const float4*)(g_all + (size_t)t*3200);
        float a = 0.f;
        #pragma unroll
        for (int i = 0; i < 4; i++) {
            int k = tid + 256*i;
            if (k < 800) {
                float4 gv = g4[k];
                a = fmaf(gv.x, wreg[i].x, a);
                a = fmaf(gv.y, wreg[i].y, a);
                a = fmaf(gv.z, wreg[i].z, a);
                a = fmaf(gv.w, wreg[i].w, a);
            }
        }
        accs[tt] = a;
    }
    int lane = tid & 63, wid = tid >> 6;
    #pragma unroll
    for (int tt = 0; tt < 8; tt++) {
        float v = accs[tt];
        #pragma unroll
        for (int s = 32; s >= 1; s >>= 1) v += __shfl_down(v, s, 64);
        if (lane == 0) red[tt][wid] = v;
    }
    __syncthreads();
    if (tid < 8)
        h_all[(size_t)(by*8 + tid)*500 + n] =
            red[tid][0] + red[tid][1] + red[tid][2] + red[tid][3] + fcb[n];
}

// ================= k_head_all: LIF2 + LI readout =================
__global__ __launch_bounds__(640) void k_head_all(
        const float* __restrict__ h_all, const float* __restrict__ outw,
        float* __restrict__ out) {
    __shared__ float spk[500];
    __shared__ float vout[10];
    int tid = threadIdx.x;
    int wid = tid >> 6, lane = tid & 63;
    float v2r = 0.f, i2r = 0.f;
    float vor = 0.f, ior = 0.f;
    #pragma unroll 1
    for (int t = 0; t < 32; t++) {
        if (tid < 500) {
            float cur = i2r;
            float vd = v2r + DTMEM*(cur - v2r);
            float z = (vd > 1.0f) ? 1.0f : 0.0f;
            v2r = (1.0f - z)*vd;
            i2r = (cur - DTSYN*cur) + h_all[t*500 + tid];
            spk[tid] = z;
        }
        __syncthreads();
        float acc = 0.f;
        for (int n = lane; n < 500; n += 64)
            acc = fmaf(spk[n], outw[wid*500 + n], acc);
        #pragma unroll
        for (int s = 32; s >= 1; s >>= 1) acc += __shfl_down(acc, s, 64);
        if (lane == 0) {
            float ij = ior + acc;
            float vn = vor + DTMEM*(ij - vor);
            ior = ij - DTSYN*ij;
            vor = vn;
            vout[wid] = vn;
        }
        __syncthreads();
        if (tid < 320) out[(size_t)t*320 + tid] = vout[tid % 10];
        __syncthreads();
    }
}

// ---------------- launcher ----------------
extern "C" void kernel_launch(void* const* d_in, const int* in_sizes, int n_in,
                              void* d_out, int out_size, void* d_ws, size_t ws_size,
                              hipStream_t stream) {
    const float* x    = (const float*)d_in[0];
    const float* b1   = (const float*)d_in[1];
    const float* b2   = (const float*)d_in[2];
    const float* w1   = (const float*)d_in[3];
    const float* w2   = (const float*)d_in[4];
    const float* fcw  = (const float*)d_in[5];
    const float* fcb  = (const float*)d_in[6];
    const float* outw = (const float*)d_in[7];
    float* ws  = (float*)d_ws;
    float* out = (float*)d_out;

    DK dk;
    {
        float g1[25], g2[25], s1 = 0.f, s2 = 0.f;
        for (int i = 0; i < 5; i++)
            for (int j = 0; j < 5; j++) {
                float ai = (float)(i - 2), aj = (float)(j - 2);
                float r2 = ai*ai + aj*aj;
                g1[i*5+j] = expf(-r2/2.0f);
                g2[i*5+j] = expf(-r2/8.0f);
                s1 += g1[i*5+j]; s2 += g2[i*5+j];
            }
        for (int k = 0; k < 25; k++) dk.v[k] = g1[k]/s1 - g2[k]/s2;
    }

    hipMemcpyAsync(ws + OW1A, w1, 1500*sizeof(float), hipMemcpyDeviceToDevice, stream);
    hipMemsetAsync(ws + OSPK, 0, 16*sizeof(float), stream);              // flag must be 0 before k_sim
    hipMemsetAsync(ws + OG, 0, (size_t)T*3200*sizeof(float), stream);    // g zero (fast path + fc1b)
    k_pre<<<dim3(10, 32), 384, 0, stream>>>(x, b1, b2, ws + OZALL, ws + OTPALL, dk);
    k_sim<<<512, 896, 0, stream>>>(ws + OZALL, ws + OW1A, (int*)(ws + OSPK));
    k_zero<<<1024, 256, 0, stream>>>(ws);                                // gated: slow path only
    k_prep<<<294, 256, 0, stream>>>(w2, ws + OW2A, (int*)(ws + OQZF),
                                    (int*)(ws + OPZF), (int*)(ws + OSZF),
                                    (const int*)(ws + OSPK));

    for (int t = 0; t <= T; ++t)
        k_step<<<736, 448, 0, stream>>>(ws, t);

    k_fc1b<<<dim3(500, 4), 256, 0, stream>>>(ws + OG, fcw, fcb, ws + OHH,
                                             (const int*)(ws + OSPK));
    k_head_all<<<1, 640, 0, stream>>>(ws + OHH, outw, out);
}

// Round 13
// 307.192 us; speedup vs baseline: 1.9090x; 1.9090x over previous
//
#include <hip/hip_runtime.h>
#include <math.h>

// ---------------- constants ----------------
#define DTMEM 0.1f   // DT*TAU_MEM_INV
#define DTSYN 0.2f   // DT*TAU_SYN_INV
#define DTTR  0.02f  // DT*TAU_PRE_INV == DT*TAU_POST_INV

static constexpr int B = 32, T = 32;
static constexpr int HD = 60, HP = 28;
static constexpr int LD = HD*HD, LP = HP*HP;

// lif0 state: slot-major [b][og:8][yh:2][i:7][tid:448] float4 (v0.x,v0.y,i0.x,i0.y)
static constexpr size_t SVI = (size_t)B*8*2*7*448*4;
// tq1: slot-major float2
static constexpr size_t SST = (size_t)B*8*2*7*448*2;
// conv2 state: slot-major [b][jgg:7][slot:6][tid:384] float4
static constexpr size_t S2  = (size_t)B*7*6*384*4;

// ---- workspace offsets (floats) ----
static constexpr size_t OW1A  = 0;                         // w1 ping (1500)
static constexpr size_t OW1B  = OW1A + 1500;               // w1 pong
static constexpr size_t OVI0  = OW1B + 1500;               // zero-region start
static constexpr size_t OTQ1  = OVI0 + SVI;
static constexpr size_t OTP2  = OTQ1 + SST;                // [B,30,28,28] master
static constexpr size_t OZ3A  = OTP2 + (size_t)B*30*LP;    // z3 ping
static constexpr size_t OZ3B  = OZ3A + (size_t)B*30*LP;    // z3 pong
static constexpr size_t OV1S  = OZ3B + (size_t)B*30*LP;
static constexpr size_t OI1S  = OV1S + S2;
static constexpr size_t OTQ2S = OI1S + S2;
static constexpr size_t OPHIA = OTQ2S + S2;                // u16 planes (376320 floats each)
static constexpr size_t OPLOA = OPHIA + 376320;
static constexpr size_t OPZ3A = OPLOA + 376320;
static constexpr size_t OPHIB = OPZ3A + 376320;
static constexpr size_t OPLOB = OPHIB + 376320;
static constexpr size_t OPZ3B = OPLOB + 376320;
static constexpr size_t OZEROEND = OPZ3B + 376320;         // zeroed by k_zero (gated!)
// precomputed DoG output + tp1 trace, all steps: [T][B][3600] each (fully written by k_pre)
static constexpr size_t OZALL  = OZEROEND;
static constexpr size_t OTPALL = OZALL + (size_t)T*B*3600;
static constexpr size_t OEPA  = OTPALL + (size_t)T*B*3600; // E partials [32][75000] f32
static constexpr size_t OEMA  = OEPA + (size_t)B*75000;
static constexpr size_t OEPB  = OEMA + (size_t)B*75000;
static constexpr size_t OEMB  = OEPB + (size_t)B*75000;
static constexpr size_t OPARTA = OEMB + (size_t)B*75000;   // part [64 slots][1500] (slot-major)
static constexpr size_t OPARTB = OPARTA + 96000;
static constexpr size_t OG    = OPARTB + 96000;            // [T][3200] (pre-zeroed!)
static constexpr size_t OHH   = OG + (size_t)T*3200;       // [T][500]
static constexpr size_t OW2A  = OHH + (size_t)T*500;       // w2 ping [100][30][28]
static constexpr size_t OW2B  = OW2A + 84000;
static constexpr size_t OCNZA = OW2B + 84000;              // int[960][4]
static constexpr size_t OCNZB = OCNZA + 3840;
static constexpr size_t OQZF  = OCNZB + 3840;              // int[512]
static constexpr size_t OPZF  = OQZF + 512;                // int[960]
static constexpr size_t OSZF  = OPZF + 960;                // int[224]
static constexpr size_t OEAA  = OSZF + 224;                // int[224] eact ping
static constexpr size_t OEAB  = OEAA + 224;                // int[224] eact pong
// corr A-plane half-1 global scratch: u16[224][8][576] each
static constexpr size_t OATH  = OEAB + 224;                // 516096 floats
static constexpr size_t OATL  = OATH + 516096;
static constexpr size_t OSPK  = OATL + 516096;             // int: any-LIF0-spike flag
static constexpr size_t OEND  = OSPK + 16;

struct DK { float v[25]; };

typedef __attribute__((ext_vector_type(8))) short bfx8;
typedef __attribute__((ext_vector_type(4))) float f32x4;

static __device__ __forceinline__ unsigned short f2bf(float f) {
    unsigned u = __float_as_uint(f);
    return (unsigned short)((u + 0x7FFFu + ((u >> 16) & 1u)) >> 16);
}
static __device__ __forceinline__ float bf2f(unsigned short h) {
    return __uint_as_float(((unsigned)h) << 16);
}

// STDP w1 pair update; part is slot-major [s:64][1500] -> coalesced row reads.
static __device__ __forceinline__ float2 w1pair(const float* w1cur, const float* pprev,
                                                int o, int pp, int t) {
    float wa = w1cur[o*50 + pp], wb = w1cur[o*50 + 25 + pp];
    if (t > 0) {
        float EpS = 0.f, EmS = 0.f;
        for (int s = 0; s < 64; ++s) {
            EpS += pprev[s*1500 + o*50 + pp];
            EmS += pprev[s*1500 + o*50 + 25 + pp];
        }
        wa = fminf(fmaxf(wa + 0.004f*fmaxf(1.f-wa,0.f)*EpS - 0.003f*fmaxf(wa,0.f)*EmS, 0.f), 1.f);
        wb = fminf(fmaxf(wb + 0.004f*fmaxf(1.f-wb,0.f)*(-EpS) - 0.003f*fmaxf(wb,0.f)*(-EmS), 0.f), 1.f);
    }
    return make_float2(wa, wb);
}

// STDP w2 update for one element; e = (j*30+c)*25+p.
static __device__ __forceinline__ float w2eff(float w, int e, int jgg,
        const int* eaR, const float* EPr, const float* EMr) {
    float ep = 0.f, em = 0.f; int any = 0;
    for (int bb = 0; bb < 32; ++bb) {
        if (eaR[bb*7 + jgg]) {
            any = 1;
            ep += EPr[(size_t)bb*75000 + e];
            em += EMr[(size_t)bb*75000 + e];
        }
    }
    if (!any) return w;
    float dwp = 0.004f * fmaxf(1.0f - w, 0.0f) * ep;
    float dwm = 0.003f * fmaxf(w, 0.0f) * em;
    return fminf(fmaxf(w + dwp - dwm, 0.0f), 1.0f);
}

union SMEM {
    struct {                              // front blocks (~29.3 KB)
        float zsh[32*60];
        float tsh[32*60];
        float red[700];
        float wd[100];
        float vish[448*4];                // vi0 staged (v.x,v.y,i.x,i.y per thread slot)
        float tqsh[448*2];                // tq1 staged / updated trace for pass-1
        int   sflags[8];
    } f;
    struct {                              // conv2+corr blocks (~41.1 KB)
        union { float spre[LP]; unsigned short sB[10656]; } u;  // conv stage | B-planes(10080)+zero(576)
        unsigned short aTH[8*576], aTL[8*576];                  // tq2 hi/lo A-planes, half (8 rows)
        unsigned int aZ4b[16*18];                               // z4 A-plane, bit-packed [16 rows][18 words]
        int sjany[16];
        int sany, sAnyTq, ganyJ;
        int sCA[30];
    } v;
};

// ================= k_pre: DoG + tp1 trace for ALL timesteps (input-only chain) =========
// Double-buffered x staging: 1 barrier/step. Same FMA order / trace recurrence as before.
__global__ __launch_bounds__(384) void k_pre(
        const float* __restrict__ x, const float* __restrict__ b1,
        const float* __restrict__ b2, float* __restrict__ zall,
        float* __restrict__ tpall, DK dk) {
    __shared__ __attribute__((aligned(16))) float xsh[2][10*64];
    int g = blockIdx.x, b = blockIdx.y, tid = threadIdx.x;
    int r0 = g*6;
    bool valid = tid < 360;
    int lr = tid / 60, col = tid - lr*60;
    float tp = 0.f;
    float bias = b1[0] - b2[0];
    if (tid < 160) {
        const float4* xs = (const float4*)(x + ((size_t)b)*4096 + (size_t)r0*64);
        ((float4*)xsh[0])[tid] = xs[tid];
    }
    __syncthreads();
    #pragma unroll 1
    for (int t = 0; t < T; ++t) {
        const float* xc = xsh[t & 1];
        if (t + 1 < T && tid < 160) {
            const float4* xs = (const float4*)(x + ((size_t)(t+1)*B + b)*4096 + (size_t)r0*64);
            ((float4*)xsh[(t+1) & 1])[tid] = xs[tid];
        }
        if (valid) {
            float a = 0.f;
            #pragma unroll
            for (int kh = 0; kh < 5; kh++)
                #pragma unroll
                for (int kw = 0; kw < 5; kw++)
                    a = fmaf(dk.v[kh*5+kw], xc[(lr+kh)*64 + col + kw], a);
            float zv = a + bias;
            tp = tp + DTTR*(zv - tp);
            size_t o = ((size_t)t*B + b)*3600 + (size_t)g*360 + tid;
            zall[o] = zv;
            tpall[o] = tp;
        }
        __syncthreads();
    }
}

// ================= k_sim: speculative LIF0 replay — sets flag if ANY spike would fire ====
// v3 = proven v1 mapping (448 thr, 14 px/thread) + double-buffered z staging (33 barriers).
// Bit-identical spike trajectory: same per-pixel kh-outer/kw-inner FMA chain, t=0 raw w1,
// t>=1 clamp(w1) (exact while no spike has occurred — part sums provably zero).
__global__ __launch_bounds__(448) void k_sim(
        const float* __restrict__ zall, const float* __restrict__ w1,
        int* __restrict__ spk) {
    __shared__ __attribute__((aligned(16))) float zsh[2][1920];
    __shared__ float wd0[100], wdC[100];
    const int og = blockIdx.x & 7, by = blockIdx.x >> 3;
    const int b = by >> 1, yh = by & 1, y0 = yh*28;
    const int tid = threadIdx.x;
    if (tid < 100) {
        int oo2 = tid / 25, pp = tid % 25;
        int o2 = og*4 + oo2; if (o2 > 29) o2 = 29;
        float wa = w1[o2*50 + pp], wb = w1[o2*50 + 25 + pp];
        wd0[tid] = wa - wb;
        wdC[tid] = fminf(fmaxf(wa, 0.f), 1.f) - fminf(fmaxf(wb, 0.f), 1.f);
    }
    int oo = tid & 3, xq = (tid >> 2) & 3, yv = tid >> 4;
    int o = og*4 + oo, xx0 = xq*14;
    bool valid = (o < 30);
    float v[14], ci[14];
    #pragma unroll
    for (int k = 0; k < 14; ++k) { v[k] = 0.f; ci[k] = 0.f; }
    bool any = false;
    {
        const float4* zs = (const float4*)(zall + ((size_t)b)*3600 + (size_t)y0*60);
        for (int i2 = tid; i2 < 480; i2 += 448) ((float4*)zsh[0])[i2] = zs[i2];
    }
    __syncthreads();
    #pragma unroll 1
    for (int t = 0; t < T; ++t) {
        const float* zc = zsh[t & 1];
        if (t + 1 < T) {
            const float4* zs = (const float4*)(zall + ((size_t)(t+1)*B + b)*3600 + (size_t)y0*60);
            for (int i2 = tid; i2 < 480; i2 += 448) ((float4*)zsh[(t+1) & 1])[i2] = zs[i2];
        }
        if (valid) {
            float acc[14];
            #pragma unroll
            for (int k = 0; k < 14; k++) acc[k] = 0.f;
            const float* wdp = (t == 0) ? wd0 : wdC;
            #pragma unroll
            for (int kh = 0; kh < 5; kh++) {
                float rr[18];
                const float2* r2 = (const float2*)&zc[(yv+kh)*HD + xx0];
                #pragma unroll
                for (int i = 0; i < 9; i++) ((float2*)rr)[i] = r2[i];
                #pragma unroll
                for (int kw = 0; kw < 5; kw++) {
                    float w = wdp[oo*25 + kh*5 + kw];
                    #pragma unroll
                    for (int k = 0; k < 14; k++) acc[k] = fmaf(w, rr[k+kw], acc[k]);
                }
            }
            #pragma unroll
            for (int e = 0; e < 14; ++e) {
                float vd = v[e] + DTMEM*(ci[e] - v[e]);
                float z = (vd > 15.0f) ? 1.0f : 0.0f;
                any = any || (z != 0.f);
                v[e] = (1.0f - z)*vd;
                ci[e] = (ci[e] - DTSYN*ci[e]) + acc[e];
            }
        }
        __syncthreads();
    }
    if (any) atomicOr(spk, 1);
}

// ================= k_zero: zero the state region, ONLY when slow path is needed =========
__global__ __launch_bounds__(256) void k_zero(float* __restrict__ ws) {
    if (((const int*)(ws + OSPK))[0] == 0) return;
    const size_t n = (OZEROEND - OVI0) / 4;   // float4 count (region is 16B-divisible)
    float4* p = (float4*)(ws + OVI0);
    float4 z; z.x = 0.f; z.y = 0.f; z.z = 0.f; z.w = 0.f;
    for (size_t i = (size_t)blockIdx.x*blockDim.x + threadIdx.x; i < n;
         i += (size_t)gridDim.x*blockDim.x)
        p[i] = z;
}

// ================= one launch per timestep, grid 736 =================
// All blocks first check the speculation flag: if no LIF0 spike ever fires, the entire
// step loop is dead (g pre-zeroed; nothing else consumed) and blocks exit immediately.
__global__ __launch_bounds__(448) void k_step(float* __restrict__ ws, int t) {
    __shared__ __attribute__((aligned(16))) SMEM sm;
    const int blk = blockIdx.x, tid = threadIdx.x;
    if (((const int*)(ws + OSPK))[0] == 0) return;   // speculation: zero-activity fast path

    if (blk < 224) {
        // ===================== conv2 + corr, step u = t-1 =====================
        const int u = t - 1;
        if (u < 0) return;
        const int cb = blk;
        const int jgg = cb % 7, b = cb / 7, jb0 = jgg*16;
        const float* w2cur = ws + ((u&1) ? OW2B : OW2A);
        float*       w2nxt = ws + ((u&1) ? OW2A : OW2B);
        const float* EPr = ws + ((u&1) ? OEPA : OEPB);   // E(u-1)
        const float* EMr = ws + ((u&1) ? OEMA : OEMB);
        float*       EPw = ws + ((u&1) ? OEPB : OEPA);   // E(u)
        float*       EMw = ws + ((u&1) ? OEMB : OEMA);
        const int*   eaR = (const int*)(ws + ((u&1) ? OEAA : OEAB));
        int*         eaW = (int*)(ws + ((u&1) ? OEAB : OEAA));
        const int*   cnzP = (const int*)(ws + ((u&1) ? OCNZB : OCNZA));
        const float* z3r = ws + ((u&1) ? OZ3B : OZ3A);
        const unsigned short* uhiR = (const unsigned short*)(ws + ((u&1) ? OPHIB : OPHIA));
        const unsigned short* uloR = (const unsigned short*)(ws + ((u&1) ? OPLOB : OPLOA));
        const unsigned short* uz3R = (const unsigned short*)(ws + ((u&1) ? OPZ3B : OPZ3A));
        unsigned short* gTH = (unsigned short*)(ws + OATH) + (size_t)cb*8*576;
        unsigned short* gTL = (unsigned short*)(ws + OATL) + (size_t)cb*8*576;
        int* szf = (int*)(ws + OSZF);
        float* g_t = ws + OG + (size_t)u*3200;

        // w2 persist (through u-1) — must run even on early-out
        if (u < 31) {
            int e = cb*448 + tid;
            if (e < 75000) {
                int j = e/750, r = e - j*750, c = r/25, p25 = r - c*25;
                size_t f = ((size_t)j*30 + c)*28 + p25;
                float w = w2cur[f];
                if (u >= 1) w = w2eff(w, e, j>>4, eaR, EPr, EMr);
                w2nxt[f] = w;
            }
        }

        if (tid == 0) { sm.v.sany = 0; sm.v.sAnyTq = 0; sm.v.ganyJ = 0; }
        if (tid < 16) sm.v.sjany[tid] = 0;
        for (int i2 = tid; i2 < 288; i2 += 448) sm.v.aZ4b[i2] = 0u;
        __syncthreads();
        if (tid < 120 && cnzP[b*120 + tid]) atomicOr(&sm.v.sany, 1);
        if (tid < 30) {
            const int* cz = cnzP + (b*30 + tid)*4;
            sm.v.sCA[tid] = (cz[0] | cz[1] | cz[2] | cz[3]);
        }
        if (u >= 1 && tid < 32 && eaR[tid*7 + jgg]) atomicOr(&sm.v.ganyJ, 1);
        __syncthreads();
        const int szv = szf[b*7 + jgg];
        if (szv && !sm.v.sany) {
            if (tid < 16 && jb0 + tid < 100) g_t[b*100 + jb0 + tid] = 0.f;
            if (u < 31 && tid == 0) eaW[b*7 + jgg] = 0;
            return;
        }
        // ---- conv2 (384 threads: jp:8, xh:2, y:24); j-pair processed sequentially ----
        const bool run = tid < 384;
        int jp = tid & 7, xh = (tid >> 3) & 1, yv = tid >> 4;
        int j0 = jb0 + jp*2;
        int ja = (j0 < 100) ? j0 : 99, jbb = (j0+1 < 100) ? j0+1 : 99;
        int xx0 = xh*12;
        float acc0[12], acc1[12];
        #pragma unroll
        for (int xq = 0; xq < 12; xq++) { acc0[xq] = 0.f; acc1[xq] = 0.f; }
        const int gJ = sm.v.ganyJ;
        #pragma unroll 1
        for (int c = 0; c < 30; ++c) {
            bool act = sm.v.sCA[c] != 0;
            __syncthreads();
            if (act) {
                const float4* src = (const float4*)(z3r + (size_t)(b*30 + c)*LP);
                for (int i2 = tid; i2 < 196; i2 += 448) ((float4*)sm.v.u.spre)[i2] = src[i2];
            }
            __syncthreads();
            if (!act) continue;
            if (run) {
                #pragma unroll 1
                for (int jj = 0; jj < 2; ++jj) {
                    int jc = jj ? jbb : ja;
                    float wa[28];
                    #pragma unroll
                    for (int i = 0; i < 7; i++)
                        ((float4*)wa)[i] = ((const float4*)(w2cur + ((size_t)jc*30 + c)*28))[i];
                    if (u >= 1 && gJ) {
                        #pragma unroll
                        for (int p25 = 0; p25 < 25; p25++)
                            wa[p25] = w2eff(wa[p25], (jc*30 + c)*25 + p25, jc>>4, eaR, EPr, EMr);
                    }
                    float* accp = jj ? acc1 : acc0;
                    #pragma unroll
                    for (int kh = 0; kh < 5; kh++) {
                        float rr[16];
                        const float4* r4 = (const float4*)&sm.v.u.spre[(yv+kh)*HP + xx0];
                        #pragma unroll
                        for (int i = 0; i < 4; i++) ((float4*)rr)[i] = r4[i];
                        #pragma unroll
                        for (int kw = 0; kw < 5; kw++) {
                            float w0 = wa[kh*5+kw];
                            #pragma unroll
                            for (int xq = 0; xq < 12; xq++)
                                accp[xq] = fmaf(w0, rr[xq+kw], accp[xq]);
                        }
                    }
                }
            }
        }
        // ---- LIF1 + tq2 + A-plane emit (half LDS / half global scratch) ----
        bool spk0 = false, spk1 = false, anyTq = false;
        if (run) {
            float4* v1p = (float4*)(ws + OV1S);
            float4* i1p = (float4*)(ws + OI1S);
            float4* t2p = (float4*)(ws + OTQ2S);
            size_t sb2 = ((size_t)(b*7 + jgg)*6)*384 + tid;
            #pragma unroll
            for (int jj = 0; jj < 2; jj++) {
                bool anyspk = false;
                int rj = jp*2 + jj;
                #pragma unroll
                for (int i = 0; i < 3; i++) {
                    size_t si = sb2 + (size_t)(jj*3 + i)*384;
                    float4 v4 = v1p[si];
                    float4 c4 = i1p[si];
                    float4 t4 = t2p[si];
                    float4 vn, in, tn4;
                    float* vp=(float*)&v4; float* cp=(float*)&c4; float* tp=(float*)&t4;
                    float* vnp=(float*)&vn; float* inp=(float*)&in; float* tnp=(float*)&tn4;
                    unsigned zb4 = 0;
                    #pragma unroll
                    for (int k = 0; k < 4; k++) {
                        float a = jj ? acc1[i*4+k] : acc0[i*4+k];
                        float vd = vp[k] + DTMEM*(cp[k] - vp[k]);
                        float z = (vd > 10.0f) ? 1.0f : 0.0f;
                        vnp[k] = (1.0f - z)*vd;
                        inp[k] = (cp[k] - DTSYN*cp[k]) + 10.0f*a;
                        tnp[k] = tp[k] + DTTR*(z - tp[k]);
                        if (z != 0.f) { zb4 |= 1u << k; anyspk = true; }
                        anyTq = anyTq || (tnp[k] != 0.f);
                    }
                    v1p[si] = vn;
                    i1p[si] = in;
                    t2p[si] = tn4;
                    int col = yv*24 + xx0 + i*4;
                    if (zb4) atomicOr(&sm.v.aZ4b[rj*18 + (col >> 5)], zb4 << (col & 31));
                    ushort4 hb, lb4;
                    unsigned short h;
                    h = f2bf(tnp[0]); hb.x = h; lb4.x = f2bf(tnp[0] - bf2f(h));
                    h = f2bf(tnp[1]); hb.y = h; lb4.y = f2bf(tnp[1] - bf2f(h));
                    h = f2bf(tnp[2]); hb.z = h; lb4.z = f2bf(tnp[2] - bf2f(h));
                    h = f2bf(tnp[3]); hb.w = h; lb4.w = f2bf(tnp[3] - bf2f(h));
                    if (rj < 8) {
                        *(ushort4*)&sm.v.aTH[rj*576 + col] = hb;
                        *(ushort4*)&sm.v.aTL[rj*576 + col] = lb4;
                    } else {
                        size_t gb = (size_t)(rj - 8)*576 + col;
                        *(ushort4*)(gTH + gb) = hb;
                        *(ushort4*)(gTL + gb) = lb4;
                    }
                }
                if (jj == 0) spk0 = anyspk; else spk1 = anyspk;
            }
            if (spk0 && j0 < 100) atomicOr(&sm.v.sjany[jp*2], 1);
            if (spk1 && j0+1 < 100) atomicOr(&sm.v.sjany[jp*2+1], 1);
            if (anyTq) atomicOr(&sm.v.sAnyTq, 1);
        }
        __syncthreads();
        if (tid < 16 && jb0 + tid < 100) g_t[b*100 + jb0 + tid] = sm.v.sjany[tid] ? 1.f : 0.f;
        if (tid == 0 && szv) szf[b*7 + jgg] = 0;
        // ---- STDP correlations, two 8-row passes (E(u) not needed at u==31) ----
        if (u < 31) {
            int m0i = 0;
            #pragma unroll
            for (int k = 0; k < 16; k++) m0i |= sm.v.sjany[k];
            bool m0 = (m0i != 0);
            bool mq = (sm.v.sAnyTq != 0);
            bool ea = m0 || mq;
            if (tid == 0) eaW[b*7 + jgg] = ea ? 1 : 0;
            if (!ea) return;
            for (int i2 = tid; i2 < 576; i2 += 448) sm.v.u.sB[10080 + i2] = 0;  // zero block
            int lane = tid & 63, wv = tid >> 6;
            int mode = wv >> 1, n = wv & 1;
            bool wact = (wv < 4);
            int r = lane & 15;
            bool r8 = (r < 8);
            int g8 = (lane >> 4) * 8;
            int p25 = n*16 + r;
            int offB1, offB2;
            {
                int offH, offL, offZ;
                if (p25 < 25) {
                    int dy = p25/5, dx = p25 - dy*5;
                    offH = ((0*5 + dx)*672 + dy*24)*2;
                    offL = ((1*5 + dx)*672 + dy*24)*2;
                    offZ = ((2*5 + dx)*672 + dy*24)*2;
                } else { offH = offL = offZ = 10080*2; }
                offB1 = (mode == 0) ? offH : offZ;
                offB2 = (mode == 0) ? offL : offZ;
            }
            float* Ew = (mode == 0) ? EPw : EMw;
            const char* sBb = (const char*)sm.v.u.sB;
            #pragma unroll 1
            for (int h = 0; h < 2; ++h) {
                if (h == 1) {
                    __syncthreads();   // pass-0 MFMA done before overwriting aTH/aTL
                    for (int i2 = tid; i2 < 1152; i2 += 448) {
                        if (i2 < 576) ((uint4*)sm.v.aTH)[i2] = ((const uint4*)gTH)[i2];
                        else ((uint4*)sm.v.aTL)[i2-576] = ((const uint4*)gTL)[i2-576];
                    }
                }
                int m0h = sm.v.sjany[h*8+0] | sm.v.sjany[h*8+1] | sm.v.sjany[h*8+2] |
                          sm.v.sjany[h*8+3] | sm.v.sjany[h*8+4] | sm.v.sjany[h*8+5] |
                          sm.v.sjany[h*8+6] | sm.v.sjany[h*8+7];
                #pragma unroll 1
                for (int c = 0; c < 30; ++c) {
                    bool cAc = sm.v.sCA[c] != 0;
                    __syncthreads();
                    {   // stage B-planes for this c
                        const size_t pbase = (size_t)(b*30 + c)*784;
                        for (int idx = tid; idx < 784; idx += 448) {
                            int rw = idx/28, col = idx - rw*28;
                            #pragma unroll
                            for (int pl = 0; pl < 3; ++pl) {
                                bool need = (pl < 2) ? m0 : (cAc && mq);
                                if (!need) continue;
                                unsigned short vvv =
                                    ((pl == 0) ? uhiR : (pl == 1) ? uloR : uz3R)[pbase + idx];
                                int base = pl*5*672 + rw*24;
                                #pragma unroll
                                for (int dx = 0; dx < 5; ++dx) {
                                    int xx = col - dx;
                                    if (xx >= 0 && xx < 24) sm.v.u.sB[base + dx*672 + xx] = vvv;
                                }
                            }
                        }
                    }
                    __syncthreads();
                    if (!wact) continue;
                    f32x4 C = (f32x4){0.f, 0.f, 0.f, 0.f};
                    bool go = (mode == 0) ? (m0h != 0) : (mq && cAc);
                    if (go) {
                        for (int ks = 0; ks < 18; ++ks) {
                            int kk = ks*32 + g8;
                            bfx8 a1 = {}, a2 = {};
                            if (mode == 0) {
                                unsigned wbits = 0;
                                if (r8) wbits = sm.v.aZ4b[(h*8 + r)*18 + ks] >> g8;
                                #pragma unroll
                                for (int k = 0; k < 8; ++k)
                                    ((short*)&a1)[k] = ((wbits >> k) & 1u) ? (short)0x3F80 : (short)0;
                                a2 = a1;
                            } else if (r8) {
                                a1 = *(const bfx8*)(sm.v.aTH + r*576 + ks*32);
                                a2 = *(const bfx8*)(sm.v.aTL + r*576 + ks*32);
                            }
                            bfx8 b1v = *(const bfx8*)(sBb + offB1 + kk*2);
                            bfx8 b2v = *(const bfx8*)(sBb + offB2 + kk*2);
                            C = __builtin_amdgcn_mfma_f32_16x16x32_bf16(a1, b1v, C, 0, 0, 0);
                            C = __builtin_amdgcn_mfma_f32_16x16x32_bf16(a2, b2v, C, 0, 0, 0);
                        }
                    }
                    if (p25 < 25 && (lane >> 4) < 2) {
                        #pragma unroll
                        for (int q = 0; q < 4; ++q) {
                            int j = jb0 + h*8 + (lane >> 4)*4 + q;
                            if (j < 100)
                                Ew[(size_t)b*75000 + ((size_t)j*30 + c)*25 + p25] = C[q];
                        }
                    }
                }
            }
        }
        return;
    }

    // ===================== front, step t =====================
    if (t >= T) return;
    const int fb = blk - 224;
    const int og = fb & 7, by = fb >> 3;
    const int b = by >> 1, yh = by & 1, y0 = yh*28;

    const float* w1cur = ws + ((t&1) ? OW1B : OW1A);
    float*       w1nxt = ws + ((t&1) ? OW1A : OW1B);
    float*       partW = ws + ((t&1) ? OPARTB : OPARTA);
    const float* pprev = ws + ((t&1) ? OPARTA : OPARTB);
    int*         cnzW  = (int*)(ws + ((t&1) ? OCNZB : OCNZA));
    float*       z3W   = ws + ((t&1) ? OZ3B : OZ3A);
    unsigned short* uhiW = (unsigned short*)(ws + ((t&1) ? OPHIB : OPHIA));
    unsigned short* uloW = (unsigned short*)(ws + ((t&1) ? OPLOB : OPLOA));
    unsigned short* uz3W = (unsigned short*)(ws + ((t&1) ? OPZ3B : OPZ3A));
    float* vi0g = ws + OVI0; float* tq1g = ws + OTQ1;
    float* tp2g = ws + OTP2;
    int* qzf = (int*)(ws + OQZF);
    int* pzf = (int*)(ws + OPZF);

    const int prow = (b*2 + yh)*1500;   // this block's part row (slot-major)
    int qzOld = qzf[(b*8 + og)*2 + yh];
    size_t sb = ((size_t)((b*8 + og)*2 + yh)*7)*448 + tid;
    float4* vi0p = (float4*)vi0g;
    float2* tq1p = (float2*)tq1g;
    {
        // batch all global staging: precomputed z/tp1 rows + vi0 (+tq1 if nonzero)
        const float4* zs = (const float4*)(ws + OZALL + ((size_t)t*B + b)*3600 + (size_t)y0*60);
        const float4* ts = (const float4*)(ws + OTPALL + ((size_t)t*B + b)*3600 + (size_t)y0*60);
        for (int i2 = tid; i2 < 480; i2 += 448) {
            ((float4*)sm.f.zsh)[i2] = zs[i2];
            ((float4*)sm.f.tsh)[i2] = ts[i2];
        }
        #pragma unroll
        for (int i = 0; i < 7; i++)
            ((float4*)sm.f.vish)[i*448 + tid] = vi0p[sb + (size_t)i*448];
        if (!qzOld) {
            #pragma unroll
            for (int i = 0; i < 7; i++)
                ((float2*)sm.f.tqsh)[i*448 + tid] = tq1p[sb + (size_t)i*448];
        }
    }
    if (tid < 100) {
        int oo2 = tid / 25, pp = tid % 25;
        int o2 = og*4 + oo2; if (o2 > 29) o2 = 29;
        float2 wp = w1pair(w1cur, pprev, o2, pp, t);
        sm.f.wd[tid] = wp.x - wp.y;
    }
    if (fb < 4) {
        int e = fb*448 + tid;
        if (e < 1500) {
            int o = e/50, r = e%50, ch = r/25, pp = r%25;
            float2 wp = w1pair(w1cur, pprev, o, pp, t);
            w1nxt[e] = ch ? wp.y : wp.x;
        }
    }
    if (tid < 8) sm.f.sflags[tid] = 0;
    __syncthreads();
    int oo = tid & 3, xq = (tid >> 2) & 3, yv = tid >> 4;
    int o = og*4 + oo, xx0 = xq*14;
    bool valid = (o < 30);
    unsigned zmask = 0;
    float qs = 0.f;
    bool anym = false;
    if (valid) {
        float acc[14];
        #pragma unroll
        for (int k = 0; k < 14; k++) acc[k] = 0.f;
        #pragma unroll
        for (int kh = 0; kh < 5; kh++) {
            float rr[18];
            const float2* r2 = (const float2*)&sm.f.zsh[(yv+kh)*HD + xx0];
            #pragma unroll
            for (int i = 0; i < 9; i++) ((float2*)rr)[i] = r2[i];
            #pragma unroll
            for (int kw = 0; kw < 5; kw++) {
                float w = sm.f.wd[oo*25 + kh*5 + kw];
                #pragma unroll
                for (int k = 0; k < 14; k++) acc[k] = fmaf(w, rr[k+kw], acc[k]);
            }
        }
        // LIF0: state from LDS (staged at top); updated v/i -> global;
        // updated trace -> tqsh (for pass-1) + gated global write.
        #pragma unroll
        for (int i = 0; i < 7; i++) {
            float4 vi = ((float4*)sm.f.vish)[i*448 + tid];
            float2 t2;
            if (qzOld) { t2.x = 0.f; t2.y = 0.f; }
            else t2 = ((float2*)sm.f.tqsh)[i*448 + tid];
            float4 vin;
            float2 tn2;
            bool sp = false;
            #pragma unroll
            for (int k = 0; k < 2; k++) {
                int e = i*2 + k;
                float vv = k ? vi.y : vi.x, cc = k ? vi.w : vi.z, tt = k ? t2.y : t2.x;
                float vd = vv + DTMEM*(cc - vv);
                float z = (vd > 15.0f) ? 1.0f : 0.0f;
                float vo = (1.0f - z)*vd;
                float io_ = (cc - DTSYN*cc) + acc[e];
                float tq = tt + DTTR*(z - tt);
                if (k) { vin.y = vo; vin.w = io_; tn2.y = tq; }
                else   { vin.x = vo; vin.z = io_; tn2.x = tq; }
                if (z != 0.f) { zmask |= 1u << e; sp = true; }
                qs += tq;
            }
            vi0p[sb + (size_t)i*448] = vin;
            ((float2*)sm.f.tqsh)[i*448 + tid] = tn2;   // own slot; no barrier needed
            if (!qzOld || sp) tq1p[sb + (size_t)i*448] = tn2;
        }
        float mx[7];
        #pragma unroll
        for (int k = 0; k < 7; k++) mx[k] = ((zmask >> (2*k)) & 3u) ? 1.0f : 0.0f;
        #pragma unroll
        for (int k = 0; k < 7; k++) {
            float pm = __shfl_xor(mx[k], 16, 64);   // y-partner (y^1)
            mx[k] = fmaxf(mx[k], pm);
        }
        if ((yv & 1) == 0) {
            int pzOld = pzf[b*30 + o];
            int py = yh*14 + (yv >> 1);
            size_t pb = ((size_t)(b*30 + o)*HP + py)*HP + xq*7;
            #pragma unroll
            for (int k = 0; k < 7; k++) {
                float m = mx[k];
                anym = anym || (m != 0.f);
                if (!pzOld || m != 0.f) {
                    z3W[pb + k] = m;
                    float tpv = pzOld ? 0.f : tp2g[pb + k];
                    float tnew = tpv + DTTR*(m - tpv);
                    tp2g[pb + k] = tnew;
                    unsigned short h = f2bf(tnew);
                    uhiW[pb + k] = h;
                    uloW[pb + k] = f2bf(tnew - bf2f(h));
                    uz3W[pb + k] = (m != 0.f) ? (unsigned short)0x3F80 : (unsigned short)0;
                }
            }
        }
    }
    if (anym) atomicOr(&sm.f.sflags[oo*2 + (xq >> 1)], 1);
    __syncthreads();
    int anyblk = sm.f.sflags[0]|sm.f.sflags[1]|sm.f.sflags[2]|sm.f.sflags[3]|
                 sm.f.sflags[4]|sm.f.sflags[5]|sm.f.sflags[6]|sm.f.sflags[7];
    if (tid < 8) {
        int o2 = og*4 + (tid >> 1);
        if (o2 < 30) cnzW[(b*30 + o2)*4 + yh*2 + (tid & 1)] = sm.f.sflags[tid];
    }
    if (tid < 4) {  // sticky plane-zero clear (benign cross-yh race: both write 0)
        int o2 = og*4 + tid;
        if (o2 < 30 && (sm.f.sflags[tid*2] | sm.f.sflags[tid*2+1])) pzf[b*30 + o2] = 0;
    }
    if (tid == 0 && qzOld && anyblk) qzf[(b*8 + og)*2 + yh] = 0;

    if (qzOld && !anyblk) {
        // tq1 was zero and no spikes fired: both correlation rows are exactly zero.
        if (tid < 100) {
            int oo2 = tid / 25, q = tid % 25;
            int o2 = og*4 + oo2;
            if (o2 < 30) {
                partW[prow + o2*50 + q] = 0.f;
                partW[prow + o2*50 + 25 + q] = 0.f;
            }
        }
        return;
    }
    int lane = tid & 63, wave = tid >> 6;
    // pass 1: minus correlation (unfold(z0) x tq1_new); tn re-read from LDS tqsh.
    {
        float a[25];
        #pragma unroll
        for (int pq = 0; pq < 25; pq++) a[pq] = 0.f;
        if (valid && qs != 0.f) {
            float tn[14];
            #pragma unroll
            for (int i = 0; i < 7; i++) {
                float2 t2 = ((float2*)sm.f.tqsh)[i*448 + tid];
                tn[2*i] = t2.x; tn[2*i+1] = t2.y;
            }
            #pragma unroll
            for (int kh = 0; kh < 5; kh++) {
                float rr[18];
                const float2* r2 = (const float2*)&sm.f.zsh[(yv+kh)*HD + xx0];
                #pragma unroll
                for (int i = 0; i < 9; i++) ((float2*)rr)[i] = r2[i];
                #pragma unroll
                for (int kw = 0; kw < 5; kw++)
                    #pragma unroll
                    for (int k = 0; k < 14; k++)
                        a[kh*5+kw] = fmaf(rr[k+kw], tn[k], a[kh*5+kw]);
            }
        }
        #pragma unroll
        for (int q = 0; q < 25; q++) {
            float v = a[q];
            v += __shfl_xor(v, 4, 64);
            v += __shfl_xor(v, 8, 64);
            v += __shfl_xor(v, 16, 64);
            v += __shfl_xor(v, 32, 64);
            if (lane < 4) sm.f.red[wave*100 + lane*25 + q] = v;
        }
    }
    __syncthreads();
    if (tid < 100) {
        int oo2 = tid / 25, q = tid % 25;
        float s = 0.f;
        #pragma unroll
        for (int w = 0; w < 7; w++) s += sm.f.red[w*100 + oo2*25 + q];
        int o2 = og*4 + oo2;
        if (o2 < 30) partW[prow + o2*50 + 25 + q] = s;
    }
    __syncthreads();
    // pass 2: plus correlation (unfold(tp1_new) x z2); z from zmask bits.
    {
        float a[25];
        #pragma unroll
        for (int pq = 0; pq < 25; pq++) a[pq] = 0.f;
        if (valid && zmask != 0u) {
            float zf[14];
            #pragma unroll
            for (int k = 0; k < 14; k++) zf[k] = ((zmask >> k) & 1u) ? 1.0f : 0.0f;
            #pragma unroll
            for (int kh = 0; kh < 5; kh++) {
                float rr[18];
                const float2* r2 = (const float2*)&sm.f.tsh[(yv+kh)*HD + xx0];
                #pragma unroll
                for (int i = 0; i < 9; i++) ((float2*)rr)[i] = r2[i];
                #pragma unroll
                for (int kw = 0; kw < 5; kw++)
                    #pragma unroll
                    for (int k = 0; k < 14; k++)
                        a[kh*5+kw] = fmaf(rr[k+kw], zf[k], a[kh*5+kw]);
            }
        }
        #pragma unroll
        for (int q = 0; q < 25; q++) {
            float v = a[q];
            v += __shfl_xor(v, 4, 64);
            v += __shfl_xor(v, 8, 64);
            v += __shfl_xor(v, 16, 64);
            v += __shfl_xor(v, 32, 64);
            if (lane < 4) sm.f.red[wave*100 + lane*25 + q] = v;
        }
    }
    __syncthreads();
    if (tid < 100) {
        int oo2 = tid / 25, q = tid % 25;
        float s = 0.f;
        #pragma unroll
        for (int w = 0; w < 7; w++) s += sm.f.red[w*100 + oo2*25 + q];
        int o2 = og*4 + oo2;
        if (o2 < 30) partW[prow + o2*50 + q] = s;
    }
}

// ================= k_prep: padded w2 + flag init (slow path only) =================
__global__ void k_prep(const float* __restrict__ w2, float* __restrict__ w2p,
                       int* __restrict__ qzf, int* __restrict__ pzf,
                       int* __restrict__ szf, const int* __restrict__ spk) {
    if (spk[0] == 0) return;   // fast path: none of these are ever read
    int e = blockIdx.x*blockDim.x + threadIdx.x;
    if (e < 75000) {
        int j = e / 750, r = e % 750, c = r / 25, p = r % 25;
        w2p[((size_t)j*30 + c)*28 + p] = w2[e];
    }
    if (e < 512) qzf[e] = 1;
    if (e < 960) pzf[e] = 1;
    if (e < 224) szf[e] = 1;
}

// ================= k_fc1b: batched fc1, grid (500 n, 4 t-quarters) =================
__global__ __launch_bounds__(256) void k_fc1b(
        const float* __restrict__ g_all, const float* __restrict__ fcw,
        const float* __restrict__ fcb, float* __restrict__ h_all,
        const int* __restrict__ spk) {
    __shared__ float red[8][4];
    int n = blockIdx.x, by = blockIdx.y, tid = threadIdx.x;
    if (spk[0] == 0) {
        // g is all-zero: h = 0*w (any order) + fcb = fcb, bit-exactly.
        if (tid < 8) h_all[(size_t)(by*8 + tid)*500 + n] = fcb[n];
        return;
    }
    const float4* w4 = (const float4*)(fcw + (size_t)n*3200);
    float4 wreg[4];
    #pragma unroll
    for (int i = 0; i < 4; i++) {
        int k = tid + 256*i;
        if (k < 800) wreg[i] = w4[k];
    }
    float accs[8];
    #pragma unroll
    for (int tt = 0; tt < 8; tt++) accs[tt] = 0.f;
    #pragma unroll 1
    for (int tt = 0; tt < 8; tt++) {
        int t = by*8 + tt;
        const float4* g4 = (const float4*)(g_all + (size_t)t*3200);
        float a = 0.f;
        #pragma unroll
        for (int i = 0; i < 4; i++) {
            int k = tid + 256*i;
            if (k < 800) {
                float4 gv = g4[k];
                a = fmaf(gv.x, wreg[i].x, a);
                a = fmaf(gv.y, wreg[i].y, a);
                a = fmaf(gv.z, wreg[i].z, a);
                a = fmaf(gv.w, wreg[i].w, a);
            }
        }
        accs[tt] = a;
    }
    int lane = tid & 63, wid = tid >> 6;
    #pragma unroll
    for (int tt = 0; tt < 8; tt++) {
        float v = accs[tt];
        #pragma unroll
        for (int s = 32; s >= 1; s >>= 1) v += __shfl_down(v, s, 64);
        if (lane == 0) red[tt][wid] = v;
    }
    __syncthreads();
    if (tid < 8)
        h_all[(size_t)(by*8 + tid)*500 + n] =
            red[tid][0] + red[tid][1] + red[tid][2] + red[tid][3] + fcb[n];
}

// ================= k_head_all: LIF2 + LI readout =================
__global__ __launch_bounds__(640) void k_head_all(
        const float* __restrict__ h_all, const float* __restrict__ outw,
        float* __restrict__ out) {
    __shared__ float spk[500];
    __shared__ float vout[10];
    int tid = threadIdx.x;
    int wid = tid >> 6, lane = tid & 63;
    float v2r = 0.f, i2r = 0.f;
    float vor = 0.f, ior = 0.f;
    #pragma unroll 1
    for (int t = 0; t < 32; t++) {
        if (tid < 500) {
            float cur = i2r;
            float vd = v2r + DTMEM*(cur - v2r);
            float z = (vd > 1.0f) ? 1.0f : 0.0f;
            v2r = (1.0f - z)*vd;
            i2r = (cur - DTSYN*cur) + h_all[t*500 + tid];
            spk[tid] = z;
        }
        __syncthreads();
        float acc = 0.f;
        for (int n = lane; n < 500; n += 64)
            acc = fmaf(spk[n], outw[wid*500 + n], acc);
        #pragma unroll
        for (int s = 32; s >= 1; s >>= 1) acc += __shfl_down(acc, s, 64);
        if (lane == 0) {
            float ij = ior + acc;
            float vn = vor + DTMEM*(ij - vor);
            ior = ij - DTSYN*ij;
            vor = vn;
            vout[wid] = vn;
        }
        __syncthreads();
        if (tid < 320) out[(size_t)t*320 + tid] = vout[tid % 10];
        __syncthreads();
    }
}

// ---------------- launcher ----------------
extern "C" void kernel_launch(void* const* d_in, const int* in_sizes, int n_in,
                              void* d_out, int out_size, void* d_ws, size_t ws_size,
                              hipStream_t stream) {
    const float* x    = (const float*)d_in[0];
    const float* b1   = (const float*)d_in[1];
    const float* b2   = (const float*)d_in[2];
    const float* w1   = (const float*)d_in[3];
    const float* w2   = (const float*)d_in[4];
    const float* fcw  = (const float*)d_in[5];
    const float* fcb  = (const float*)d_in[6];
    const float* outw = (const float*)d_in[7];
    float* ws  = (float*)d_ws;
    float* out = (float*)d_out;

    DK dk;
    {
        float g1[25], g2[25], s1 = 0.f, s2 = 0.f;
        for (int i = 0; i < 5; i++)
            for (int j = 0; j < 5; j++) {
                float ai = (float)(i - 2), aj = (float)(j - 2);
                float r2 = ai*ai + aj*aj;
                g1[i*5+j] = expf(-r2/2.0f);
                g2[i*5+j] = expf(-r2/8.0f);
                s1 += g1[i*5+j]; s2 += g2[i*5+j];
            }
        for (int k = 0; k < 25; k++) dk.v[k] = g1[k]/s1 - g2[k]/s2;
    }

    hipMemcpyAsync(ws + OW1A, w1, 1500*sizeof(float), hipMemcpyDeviceToDevice, stream);
    hipMemsetAsync(ws + OSPK, 0, 16*sizeof(float), stream);              // flag must be 0 before k_sim
    hipMemsetAsync(ws + OG, 0, (size_t)T*3200*sizeof(float), stream);    // g zero (fast path + fc1b)
    k_pre<<<dim3(10, 32), 384, 0, stream>>>(x, b1, b2, ws + OZALL, ws + OTPALL, dk);
    k_sim<<<512, 448, 0, stream>>>(ws + OZALL, ws + OW1A, (int*)(ws + OSPK));
    k_zero<<<1024, 256, 0, stream>>>(ws);                                // gated: slow path only
    k_prep<<<294, 256, 0, stream>>>(w2, ws + OW2A, (int*)(ws + OQZF),
                                    (int*)(ws + OPZF), (int*)(ws + OSZF),
                                    (const int*)(ws + OSPK));

    for (int t = 0; t <= T; ++t)
        k_step<<<736, 448, 0, stream>>>(ws, t);

    k_fc1b<<<dim3(500, 4), 256, 0, stream>>>(ws + OG, fcw, fcb, ws + OHH,
                                             (const int*)(ws + OSPK));
    k_head_all<<<1, 640, 0, stream>>>(ws + OHH, outw, out);
}